// Round 1
// baseline (614.091 us; speedup 1.0000x reference)
//
#include <hip/hip_runtime.h>

#define FDIM 32

// h = features @ kernels  (one thread per (node, f_out))
__global__ __launch_bounds__(256) void k_h(const float* __restrict__ feat,
                                           const float* __restrict__ kern,
                                           float* __restrict__ h, int N) {
    __shared__ float sk[FDIM * FDIM];
    int tid = threadIdx.x;
    for (int i = tid; i < FDIM * FDIM; i += 256) sk[i] = kern[i];
    __syncthreads();
    int gid = blockIdx.x * 256 + tid;
    int n = gid >> 5;
    int f = gid & 31;
    if (n >= N) return;
    const float* fr = feat + (size_t)n * FDIM;
    float acc = 0.f;
#pragma unroll
    for (int k = 0; k < FDIM; ++k) acc = fmaf(fr[k], sk[k * FDIM + f], acc);
    h[(size_t)n * FDIM + f] = acc;
}

// out-degree of each src node (float accumulate to match reference semantics)
__global__ __launch_bounds__(256) void k_deg(const int* __restrict__ srcs,
                                             float* __restrict__ deg, int E) {
    int e = blockIdx.x * 256 + threadIdx.x;
    if (e >= E) return;
    atomicAdd(&deg[srcs[e]], 1.0f);
}

// norm = clip(deg,1)^-0.5
__global__ __launch_bounds__(256) void k_norm(const float* __restrict__ deg,
                                              float* __restrict__ norm, int N) {
    int n = blockIdx.x * 256 + threadIdx.x;
    if (n >= N) return;
    norm[n] = rsqrtf(fmaxf(deg[n], 1.0f));
}

// out[n][f] = biases[f]  (init; scatter accumulates on top)
__global__ __launch_bounds__(256) void k_outinit(float* __restrict__ out,
                                                 const float* __restrict__ bias,
                                                 int total) {
    int gid = blockIdx.x * 256 + threadIdx.x;
    if (gid >= total) return;
    out[gid] = bias[gid & 31];
}

// per edge: out[src][:] += norm[src]*w*norm[dst] * h[dst][:]
// 32 lanes per edge: lane handles one feature -> coalesced gather + coalesced atomics
__global__ __launch_bounds__(256) void k_scatter(const int* __restrict__ srcs,
                                                 const int* __restrict__ dsts,
                                                 const float* __restrict__ ew,
                                                 const float* __restrict__ h,
                                                 const float* __restrict__ norm,
                                                 float* __restrict__ out, int E) {
    int gid = blockIdx.x * 256 + threadIdx.x;
    int e = gid >> 5;
    int f = gid & 31;
    if (e >= E) return;
    int s = srcs[e];
    int d = dsts[e];
    float w = norm[s] * ew[e] * norm[d];
    float v = h[(size_t)d * FDIM + f] * w;
    atomicAdd(&out[(size_t)s * FDIM + f], v);
}

extern "C" void kernel_launch(void* const* d_in, const int* in_sizes, int n_in,
                              void* d_out, int out_size, void* d_ws, size_t ws_size,
                              hipStream_t stream) {
    const float* feat = (const float*)d_in[0];
    const int*   srcs = (const int*)d_in[1];
    const int*   dsts = (const int*)d_in[2];
    const float* ew   = (const float*)d_in[3];
    const float* kern = (const float*)d_in[4];
    const float* bias = (const float*)d_in[5];
    float* out = (float*)d_out;

    int N = in_sizes[0] / FDIM;
    int E = in_sizes[1];

    float* h    = (float*)d_ws;            // N*32 floats
    float* deg  = h + (size_t)N * FDIM;    // N floats
    float* norm = deg + N;                 // N floats

    hipMemsetAsync(deg, 0, (size_t)N * sizeof(float), stream);

    int nf = N * FDIM;
    k_h<<<(nf + 255) / 256, 256, 0, stream>>>(feat, kern, h, N);
    k_deg<<<(E + 255) / 256, 256, 0, stream>>>(srcs, deg, E);
    k_norm<<<(N + 255) / 256, 256, 0, stream>>>(deg, norm, N);
    k_outinit<<<(nf + 255) / 256, 256, 0, stream>>>(out, bias, nf);

    long long scatter_threads = (long long)E * FDIM;
    int scatter_blocks = (int)((scatter_threads + 255) / 256);
    k_scatter<<<scatter_blocks, 256, 0, stream>>>(srcs, dsts, ew, h, norm, out, E);
}

// Round 2
// 490.858 us; speedup vs baseline: 1.2511x; 1.2511x over previous
//
#include <hip/hip_runtime.h>

#define FDIM 32

// ---------------- h = features @ kernels ----------------
__global__ __launch_bounds__(256) void k_h(const float* __restrict__ feat,
                                           const float* __restrict__ kern,
                                           float* __restrict__ h, int N) {
    __shared__ float sk[FDIM * FDIM];
    int tid = threadIdx.x;
    for (int i = tid; i < FDIM * FDIM; i += 256) sk[i] = kern[i];
    __syncthreads();
    int gid = blockIdx.x * 256 + tid;
    int n = gid >> 5;
    int f = gid & 31;
    if (n >= N) return;
    const float* fr = feat + (size_t)n * FDIM;
    float acc = 0.f;
#pragma unroll
    for (int k = 0; k < FDIM; ++k) acc = fmaf(fr[k], sk[k * FDIM + f], acc);
    h[(size_t)n * FDIM + f] = acc;
}

// ---------------- per-src edge counts (int) ----------------
__global__ __launch_bounds__(256) void k_count(const int* __restrict__ srcs,
                                               unsigned* __restrict__ cnt, int E) {
    int e = blockIdx.x * 256 + threadIdx.x;
    if (e >= E) return;
    atomicAdd(&cnt[srcs[e]], 1u);
}

// ---------------- norm = clip(cnt,1)^-0.5 ----------------
__global__ __launch_bounds__(256) void k_norm(const unsigned* __restrict__ cnt,
                                              float* __restrict__ norm, int N) {
    int n = blockIdx.x * 256 + threadIdx.x;
    if (n >= N) return;
    norm[n] = rsqrtf(fmaxf((float)cnt[n], 1.0f));
}

// ---------------- 3-kernel exclusive scan over cnt[N] ----------------
// chunk = 1024 elements per block
__global__ __launch_bounds__(256) void k_blocksum(const unsigned* __restrict__ cnt,
                                                  unsigned* __restrict__ bsum, int N) {
    int b = blockIdx.x, t = threadIdx.x;
    int base = b * 1024;
    unsigned s = 0;
    for (int i = t; i < 1024; i += 256) {
        int idx = base + i;
        if (idx < N) s += cnt[idx];
    }
    __shared__ unsigned red[256];
    red[t] = s;
    __syncthreads();
    for (int off = 128; off > 0; off >>= 1) {
        if (t < off) red[t] += red[t + off];
        __syncthreads();
    }
    if (t == 0) bsum[b] = red[0];
}

// single block: exclusive scan of nb (<=256) block sums
__global__ __launch_bounds__(256) void k_scan_bsum(const unsigned* __restrict__ bsum,
                                                   unsigned* __restrict__ boff, int nb) {
    __shared__ unsigned tmp[256];
    int t = threadIdx.x;
    unsigned v = (t < nb) ? bsum[t] : 0u;
    tmp[t] = v;
    __syncthreads();
    for (int off = 1; off < 256; off <<= 1) {
        unsigned add = (t >= off) ? tmp[t - off] : 0u;
        __syncthreads();
        tmp[t] += add;
        __syncthreads();
    }
    if (t < nb) boff[t] = tmp[t] - v;  // exclusive
}

// per-block exclusive scan (4 elems/thread) + block offset -> rowstart & cursor
__global__ __launch_bounds__(256) void k_scan_final(const unsigned* __restrict__ cnt,
                                                    const unsigned* __restrict__ boff,
                                                    unsigned* __restrict__ rowstart,
                                                    unsigned* __restrict__ cursor, int N) {
    int b = blockIdx.x, t = threadIdx.x;
    int base = b * 1024 + t * 4;
    unsigned v[4];
    unsigned s = 0;
#pragma unroll
    for (int k = 0; k < 4; ++k) {
        int idx = base + k;
        v[k] = (idx < N) ? cnt[idx] : 0u;
        s += v[k];
    }
    __shared__ unsigned tmp[256];
    tmp[t] = s;
    __syncthreads();
    unsigned inc = s;
    for (int off = 1; off < 256; off <<= 1) {
        unsigned add = (t >= off) ? tmp[t - off] : 0u;
        __syncthreads();
        tmp[t] += add;
        __syncthreads();
    }
    unsigned run = boff[b] + (tmp[t] - inc);
#pragma unroll
    for (int k = 0; k < 4; ++k) {
        int idx = base + k;
        if (idx < N) {
            rowstart[idx] = run;
            cursor[idx] = run;
            run += v[k];
        }
    }
}

// ---------------- bin edges into CSR buckets with per-edge coefficient ----------------
__global__ __launch_bounds__(256) void k_binscatter(const int* __restrict__ srcs,
                                                    const int* __restrict__ dsts,
                                                    const float* __restrict__ ew,
                                                    const float* __restrict__ norm,
                                                    unsigned* __restrict__ cursor,
                                                    float2* __restrict__ sorted, int E) {
    int e = blockIdx.x * 256 + threadIdx.x;
    if (e >= E) return;
    int s = srcs[e];
    int d = dsts[e];
    float w = norm[s] * ew[e] * norm[d];
    unsigned pos = atomicAdd(&cursor[s], 1u);
    sorted[pos] = make_float2(__int_as_float(d), w);
}

// ---------------- gather: 32 lanes per src row, single write per row ----------------
__global__ __launch_bounds__(256) void k_gather(const unsigned* __restrict__ rowstart,
                                                const unsigned* __restrict__ cnt,
                                                const float2* __restrict__ sorted,
                                                const float* __restrict__ h,
                                                const float* __restrict__ bias,
                                                float* __restrict__ out, int N) {
    int gid = blockIdx.x * 256 + threadIdx.x;
    int n = gid >> 5;
    int f = gid & 31;
    if (n >= N) return;
    unsigned start = rowstart[n];
    unsigned len = cnt[n];
    const float2* p = sorted + start;
    float acc = bias[f];
    unsigned j = 0;
    for (; j + 4 <= len; j += 4) {
        float2 e0 = p[j], e1 = p[j + 1], e2 = p[j + 2], e3 = p[j + 3];
        float h0 = h[(size_t)__float_as_int(e0.x) * FDIM + f];
        float h1 = h[(size_t)__float_as_int(e1.x) * FDIM + f];
        float h2 = h[(size_t)__float_as_int(e2.x) * FDIM + f];
        float h3 = h[(size_t)__float_as_int(e3.x) * FDIM + f];
        acc = fmaf(e0.y, h0, acc);
        acc = fmaf(e1.y, h1, acc);
        acc = fmaf(e2.y, h2, acc);
        acc = fmaf(e3.y, h3, acc);
    }
    for (; j < len; ++j) {
        float2 e0 = p[j];
        acc = fmaf(e0.y, h[(size_t)__float_as_int(e0.x) * FDIM + f], acc);
    }
    out[(size_t)n * FDIM + f] = acc;
}

extern "C" void kernel_launch(void* const* d_in, const int* in_sizes, int n_in,
                              void* d_out, int out_size, void* d_ws, size_t ws_size,
                              hipStream_t stream) {
    const float* feat = (const float*)d_in[0];
    const int*   srcs = (const int*)d_in[1];
    const int*   dsts = (const int*)d_in[2];
    const float* ew   = (const float*)d_in[3];
    const float* kern = (const float*)d_in[4];
    const float* bias = (const float*)d_in[5];
    float* out = (float*)d_out;

    int N = in_sizes[0] / FDIM;
    int E = in_sizes[1];
    int nb = (N + 1023) / 1024;  // <= 256 required

    // workspace layout (all 4/8-byte aligned; d_ws assumed >= ~41 MB)
    char* w = (char*)d_ws;
    float*    h        = (float*)w;              w += (size_t)N * FDIM * sizeof(float);
    float2*   sorted   = (float2*)w;             w += (size_t)E * sizeof(float2);
    unsigned* cnt      = (unsigned*)w;           w += (size_t)N * sizeof(unsigned);
    unsigned* rowstart = (unsigned*)w;           w += (size_t)N * sizeof(unsigned);
    unsigned* cursor   = (unsigned*)w;           w += (size_t)N * sizeof(unsigned);
    float*    norm     = (float*)w;              w += (size_t)N * sizeof(float);
    unsigned* bsum     = (unsigned*)w;           w += 256 * sizeof(unsigned);
    unsigned* boff     = (unsigned*)w;           w += 256 * sizeof(unsigned);

    hipMemsetAsync(cnt, 0, (size_t)N * sizeof(unsigned), stream);

    int nf = N * FDIM;
    k_h<<<(nf + 255) / 256, 256, 0, stream>>>(feat, kern, h, N);
    k_count<<<(E + 255) / 256, 256, 0, stream>>>(srcs, cnt, E);
    k_norm<<<(N + 255) / 256, 256, 0, stream>>>(cnt, norm, N);
    k_blocksum<<<nb, 256, 0, stream>>>(cnt, bsum, N);
    k_scan_bsum<<<1, 256, 0, stream>>>(bsum, boff, nb);
    k_scan_final<<<nb, 256, 0, stream>>>(cnt, boff, rowstart, cursor, N);
    k_binscatter<<<(E + 255) / 256, 256, 0, stream>>>(srcs, dsts, ew, norm, cursor, sorted, E);
    k_gather<<<(nf + 255) / 256, 256, 0, stream>>>(rowstart, cnt, sorted, h, bias, out, N);
}